// Round 9
// baseline (5560.426 us; speedup 1.0000x reference)
//
#include <hip/hip_runtime.h>

// Net_39135742001869: S2VT video-caption LSTM (enc 80 + dec 39 steps), bf16 MFMA.
// R9: R8 structure (3-stage A/B/C, LDS weights, swapped MFMA) with the exchange protocol
// replaced by SENTINEL POLL-ON-DATA: no flags, no drains, no per-step __syncthreads.

typedef unsigned short u16;
typedef unsigned int u32;
typedef unsigned long long u64;
typedef __attribute__((ext_vector_type(8))) short s8v;   // 8 x bf16
typedef __attribute__((ext_vector_type(4))) float f4v;   // MFMA accumulator

#define VOC   6000
#define VOCP  6144
#define HSTR  65536       // 256*256 h-history slot stride (elems)
#define YSTR  262144      // 256*1024 y slot stride (elems)
#define SENT  0xFFFFFFFFFFFFFFFFull   // 4x bf16 NaN pattern: unreachable as f2b output

__device__ __forceinline__ u16 f2b(float f) {
  unsigned u = __float_as_uint(f);
  return (u16)((u + 0x7fffu + ((u >> 16) & 1u)) >> 16);   // RNE f32->bf16
}
__device__ __forceinline__ float b2f(u16 u) { return __uint_as_float(((unsigned)u) << 16); }
__device__ __forceinline__ float sigm(float x) { return 1.f / (1.f + __expf(-x)); }
__device__ __forceinline__ float tanh_f(float x) {
  float e = __expf(-2.f * fabsf(x));
  float t = (1.f - e) / (1.f + e);
  return x >= 0.f ? t : -t;
}
__device__ __forceinline__ u64 lda64(const u64* p) {
  return __hip_atomic_load(p, __ATOMIC_RELAXED, __HIP_MEMORY_SCOPE_AGENT);
}
__device__ __forceinline__ void sta64(u64* p, u64 v) {
  __hip_atomic_store(p, v, __ATOMIC_RELAXED, __HIP_MEMORY_SCOPE_AGENT);
}
union U16B { u64 q[2]; s8v v; };

// ---------------- f32 -> bf16 row-permuted conversion: dst[tl*256+b] = src[b*T+toff+tl]
__global__ __launch_bounds__(256) void conv_tr(const float* __restrict__ src,
                                               u16* __restrict__ dst, int T, int D, int toff) {
  const int tl = blockIdx.x >> 8, b = blockIdx.x & 255;
  const float* s = src + ((size_t)b * T + toff + tl) * D;
  u16* d = dst + (size_t)blockIdx.x * D;
  for (int i = threadIdx.x * 8; i < D; i += 2048) {
    float4 a = *(const float4*)(s + i);
    float4 c = *(const float4*)(s + i + 4);
    unsigned w0 = (unsigned)f2b(a.x) | ((unsigned)f2b(a.y) << 16);
    unsigned w1 = (unsigned)f2b(a.z) | ((unsigned)f2b(a.w) << 16);
    unsigned w2 = (unsigned)f2b(c.x) | ((unsigned)f2b(c.y) << 16);
    unsigned w3 = (unsigned)f2b(c.z) | ((unsigned)f2b(c.w) << 16);
    *(int4*)(d + i) = make_int4((int)w0, (int)w1, (int)w2, (int)w3);
  }
}

// ---------------- weight pack (f32 -> bf16) --------------------------------------------
__global__ void pack_bf16(u16* __restrict__ dst, int dld, int doff,
                          const float* __restrict__ src, int sld, int soff,
                          int Wc, int R, int Rsrc) {
  int i = blockIdx.x * 256 + threadIdx.x;
  if (i >= Wc * R) return;
  int r = i / Wc, c = i - r * Wc;
  float v = (r < Rsrc) ? src[(size_t)r * sld + soff + c] : 0.f;
  dst[(size_t)r * dld + doff + c] = f2b(v);
}

// ---------------- recurrence weight pack: Wpk[st][cs][lr][k], lr=(q*4+w)*16+fr ---------
__global__ __launch_bounds__(256) void wpack(u16* __restrict__ dst,
                                             const float* __restrict__ Whh1,
                                             const float* __restrict__ Wih2,
                                             const float* __restrict__ Whh2) {
  int idx = blockIdx.x * 256 + threadIdx.x;
  if (idx >= 786432) return;
  int k = idx & 255, lr = (idx >> 8) & 255, cs = (idx >> 16) & 3, st = idx >> 18;
  int q = lr >> 6, w = (lr >> 4) & 3, fr = lr & 15;
  int g = q * 256 + cs * 64 + w * 16 + fr;
  float v = (st == 0) ? Whh1[(size_t)g * 256 + k]
          : (st == 1) ? Wih2[(size_t)g * 512 + 256 + k]
                      : Whh2[(size_t)g * 256 + k];
  dst[idx] = f2b(v);
}

__global__ void bias_setup(const float* __restrict__ bi1, const float* __restrict__ bh1,
                           const float* __restrict__ bi2, const float* __restrict__ bh2,
                           const float* __restrict__ bo,
                           float* __restrict__ b1s, float* __restrict__ b2s,
                           float* __restrict__ bop) {
  int i = blockIdx.x * 256 + threadIdx.x;
  if (i < 1024) { b1s[i] = bi1[i] + bh1[i]; b2s[i] = bi2[i] + bh2[i]; }
  if (i < VOCP) bop[i] = (i < VOC) ? bo[i] : -1e30f;
}

// ---------------- targets = argmax(caption_one_hot[b, d+1, :]) -------------------------
__global__ __launch_bounds__(256) void argmax_kernel(const float* __restrict__ coh,
                                                     int* __restrict__ tgt) {
  const int d = blockIdx.x >> 8;
  const int b = blockIdx.x & 255;
  const float4* row = (const float4*)(coh + ((size_t)b * 40 + (d + 1)) * VOC);
  float best = -3.4e38f; int bi = 0;
  for (int v = threadIdx.x; v < VOC / 4; v += 256) {
    float4 x = row[v];
    float vals[4] = {x.x, x.y, x.z, x.w};
#pragma unroll
    for (int j = 0; j < 4; ++j)
      if (vals[j] > best) { best = vals[j]; bi = v * 4 + j; }
  }
#pragma unroll
  for (int o = 1; o < 64; o <<= 1) {
    float ov = __shfl_xor(best, o);
    int   oi = __shfl_xor(bi, o);
    if (ov > best || (ov == best && oi < bi)) { best = ov; bi = oi; }
  }
  __shared__ float sv[4]; __shared__ int si[4];
  if ((threadIdx.x & 63) == 0) { sv[threadIdx.x >> 6] = best; si[threadIdx.x >> 6] = bi; }
  __syncthreads();
  if (threadIdx.x == 0) {
    for (int i = 1; i < 4; ++i)
      if (sv[i] > best || (sv[i] == best && si[i] < bi)) { best = sv[i]; bi = si[i]; }
    tgt[blockIdx.x] = bi;   // [d][b]
  }
}

// ---------------- GEMM: acc = A_bf16[M][K] * Bw_bf16[N][K]^T (+bias) -------------------
// grid (M/128, N/256). MODE 0: time-major bf16 out (ld 1024, row moff+m).
// MODE 2: fused NLL partials. XCD-bijective swizzle on the m-tile index.
template <int MODE>
__global__ __launch_bounds__(256) void gemm_bb(
    const u16* __restrict__ A, const u16* __restrict__ Bw,
    const float* __restrict__ bias, void* __restrict__ out0,
    float* __restrict__ ps, float* __restrict__ tgtlog, const int* __restrict__ tgt,
    int K, int moff)
{
  const int nx = gridDim.x;
  const int qq = nx >> 3, rm = nx & 7;
  const int xcd = (int)blockIdx.x & 7, pos = (int)blockIdx.x >> 3;
  const int mt = (xcd < rm) ? (xcd * (qq + 1) + pos)
                            : (rm * (qq + 1) + (xcd - rm) * qq + pos);
  const int m0 = mt * 128;
  const int n0 = blockIdx.y * 256;
  const int tid = threadIdx.x;
  const int lane = tid & 63;
  const int wid = tid >> 6;
  const int wm = wid >> 1, wn = wid & 1;
  const int fr = lane & 15;
  const int fk = (lane >> 4) * 8;
  const int rq = lane >> 4;

  __shared__ u16 As[128][72];
  __shared__ u16 Bs[256][72];
  f4v acc[4][8] = {};

  const int ar = tid >> 1, ac = (tid & 1) * 32;
  int4 av[4], bv[8];
  {
    const u16* ap = A + (size_t)(m0 + ar) * K + ac;
    const u16* bp = Bw + (size_t)(n0 + tid) * K;
#pragma unroll
    for (int v = 0; v < 4; ++v) av[v] = *(const int4*)(ap + v * 8);
#pragma unroll
    for (int v = 0; v < 8; ++v) bv[v] = *(const int4*)(bp + v * 8);
  }
#pragma unroll 1
  for (int k0 = 0; k0 < K; k0 += 64) {
    __syncthreads();
#pragma unroll
    for (int v = 0; v < 4; ++v) *(int4*)&As[ar][ac + v * 8] = av[v];
#pragma unroll
    for (int v = 0; v < 8; ++v) *(int4*)&Bs[tid][v * 8] = bv[v];
    __syncthreads();
    if (k0 + 64 < K) {
      const u16* ap = A + (size_t)(m0 + ar) * K + k0 + 64 + ac;
      const u16* bp = Bw + (size_t)(n0 + tid) * K + k0 + 64;
#pragma unroll
      for (int v = 0; v < 4; ++v) av[v] = *(const int4*)(ap + v * 8);
#pragma unroll
      for (int v = 0; v < 8; ++v) bv[v] = *(const int4*)(bp + v * 8);
    }
#pragma unroll
    for (int ks = 0; ks < 2; ++ks) {
      const int kb = ks * 32 + fk;
      s8v a[4], b[8];
#pragma unroll
      for (int i = 0; i < 4; ++i) a[i] = *(const s8v*)&As[wm * 64 + i * 16 + fr][kb];
#pragma unroll
      for (int j = 0; j < 8; ++j) b[j] = *(const s8v*)&Bs[wn * 128 + j * 16 + fr][kb];
#pragma unroll
      for (int i = 0; i < 4; ++i)
#pragma unroll
        for (int j = 0; j < 8; ++j)
          acc[i][j] = __builtin_amdgcn_mfma_f32_16x16x32_bf16(a[i], b[j], acc[i][j], 0, 0, 0);
    }
  }

  float bz[8];
#pragma unroll
  for (int j = 0; j < 8; ++j) bz[j] = bias[n0 + wn * 128 + j * 16 + fr];

  if (MODE == 2) {
    const int tile = blockIdx.y * 2 + wn;
    float* pm = (float*)out0;
#pragma unroll
    for (int i = 0; i < 4; ++i) {
#pragma unroll
      for (int r = 0; r < 4; ++r) {
        const int row = m0 + wm * 64 + i * 16 + rq * 4 + r;
        const int tg = tgt[row];
        float vj[8]; float m = -1e30f;
#pragma unroll
        for (int j = 0; j < 8; ++j) {
          const int n = n0 + wn * 128 + j * 16 + fr;
          float v = acc[i][j][r] + bz[j];
          vj[j] = v;
          m = fmaxf(m, v);
          if (n == tg) tgtlog[row] = v;
        }
#pragma unroll
        for (int o = 1; o < 16; o <<= 1) m = fmaxf(m, __shfl_xor(m, o));
        float s = 0.f;
#pragma unroll
        for (int j = 0; j < 8; ++j) s += __expf(vj[j] - m);
#pragma unroll
        for (int o = 1; o < 16; o <<= 1) s += __shfl_xor(s, o);
        if (fr == 0) { pm[(size_t)row * 48 + tile] = m; ps[(size_t)row * 48 + tile] = s; }
      }
    }
  } else {
    u16* X = (u16*)out0;
#pragma unroll
    for (int i = 0; i < 4; ++i)
#pragma unroll
      for (int r = 0; r < 4; ++r) {
        const int mrow = m0 + wm * 64 + i * 16 + rq * 4 + r;
        u16* crow = X + (size_t)(moff + mrow) * 1024;
#pragma unroll
        for (int j = 0; j < 8; ++j)
          crow[n0 + wn * 128 + j * 16 + fr] = f2b(acc[i][j][r] + bz[j]);
      }
  }
}

// ---------------- 3-stage recurrence, sentinel poll-on-data ----------------------------
// 48 blocks x 256 thr (4 waves), 128KB LDS weights. Stage = bid>>4 (A / B / C).
// Block (rg, cs): batch rows rg*64..+64 x h/gate cols cs*64..+64. Swapped mfma(W,h).
// Histories [120][256][256] (slot s+1 = h(s); slot 0 zeros; slots 1.. PRE-POISONED to
// SENT). ybuf[119][256][1024] pre-poisoned. Producers fire sc1 u64 stores only;
// consumers batch-load needed u64s and re-poll the still-sentinel ones.
__global__ __launch_bounds__(256, 1) void recur_kernel(
    const u16* __restrict__ X1t,      // [80][256][1024] bf16, b1 folded
    const u16* __restrict__ Xct,      // [40][256][1024] bf16, b2 folded
    const float* __restrict__ b1sum, const float* __restrict__ b2sum,
    const u16* __restrict__ Wpk,      // [3][4][256][256] packed weights
    u16* __restrict__ h1hist, u16* __restrict__ h2hist,
    u16* __restrict__ ybuf)
{
  __shared__ u16 wlds[256 * 256];     // 128 KiB, XOR-swizzled (granule ^= row&7)
  const int tid = threadIdx.x, lane = tid & 63, w = tid >> 6;
  const int stage = blockIdx.x >> 4, sub = blockIdx.x & 15;
  const int rg = sub >> 2, cs = sub & 3;
  const int fr = lane & 15, rq = lane >> 4;

  // one-time: weight slice -> LDS, swizzled
  {
    const u16* wsrc = Wpk + (size_t)(stage * 4 + cs) * 65536;
    for (int i = tid; i < 8192; i += 256) {
      int lr = i >> 5, c8 = i & 31;
      int4 v = *(const int4*)(wsrc + lr * 256 + c8 * 8);
      *(int4*)&wlds[lr * 256 + ((c8 ^ (lr & 7)) * 8)] = v;
    }
  }
  float br[16];
  {
    const float* bs = (stage == 2) ? b2sum : b1sum;
#pragma unroll
    for (int q = 0; q < 4; ++q)
#pragma unroll
      for (int r = 0; r < 4; ++r)
        br[q * 4 + r] = bs[q * 256 + cs * 64 + w * 16 + rq * 4 + r];
  }
  __syncthreads();

  float creg[4][4] = {};
  const int hcol = cs * 64 + w * 16 + rq * 4;

#pragma unroll 1
  for (int s = 0; s < 119; ++s) {
    if (stage == 0) {                  // ================= A: LSTM1 =================
      u64 xa[4][4];
      if (s < 80) {
        const u16* xb = X1t + ((size_t)s * 256) * 1024;
#pragma unroll
        for (int q = 0; q < 4; ++q)
#pragma unroll
          for (int bt = 0; bt < 4; ++bt)
            xa[q][bt] = *(const u64*)(xb + (size_t)(rg * 64 + bt * 16 + fr) * 1024 +
                                      q * 256 + hcol);
      }
      // ---- poll-on-data: h1(s-1) = slot s (slot 0 is real zeros -> instant) ----
      U16B hb[4][8];
      {
        const u16* hbase = h1hist + (size_t)s * HSTR;
        u32 pend = 0xFFFFFFFFu;
        while (true) {
#pragma unroll
          for (int bt = 0; bt < 4; ++bt) {
            const u64* hp = (const u64*)(hbase + (size_t)(rg * 64 + bt * 16 + fr) * 256 +
                                         rq * 8);
#pragma unroll
            for (int kk = 0; kk < 8; ++kk)
              if (pend & (1u << (bt * 8 + kk))) {
                hb[bt][kk].q[0] = lda64(hp + kk * 4);
                hb[bt][kk].q[1] = lda64(hp + kk * 4 + 1);
              }
          }
          bool done = true;
#pragma unroll
          for (int bt = 0; bt < 4; ++bt)
#pragma unroll
            for (int kk = 0; kk < 8; ++kk)
              if (pend & (1u << (bt * 8 + kk))) {
                if (hb[bt][kk].q[0] != SENT && hb[bt][kk].q[1] != SENT)
                  pend &= ~(1u << (bt * 8 + kk));
                else done = false;
              }
          if (__all(done)) break;
          __builtin_amdgcn_s_sleep(1);
        }
      }
      f4v acc[4][4] = {};
#pragma unroll
      for (int kk = 0; kk < 8; ++kk)
#pragma unroll
        for (int q = 0; q < 4; ++q) {
          s8v wf = *(const s8v*)&wlds[((q * 4 + w) * 16 + fr) * 256 +
                                      (((kk * 4 + rq) ^ (fr & 7)) * 8)];
#pragma unroll
          for (int bt = 0; bt < 4; ++bt)
            acc[q][bt] = __builtin_amdgcn_mfma_f32_16x16x32_bf16(wf, hb[bt][kk].v,
                                                                 acc[q][bt], 0, 0, 0);
        }
      u16* hw = h1hist + (size_t)(s + 1) * HSTR;
#pragma unroll
      for (int bt = 0; bt < 4; ++bt) {
        u64 hp = 0;
#pragma unroll
        for (int r = 0; r < 4; ++r) {
          float g0 = acc[0][bt][r], g1 = acc[1][bt][r];
          float g2 = acc[2][bt][r], g3 = acc[3][bt][r];
          if (s < 80) {
            g0 += b2f((u16)(xa[0][bt] >> (r * 16)));
            g1 += b2f((u16)(xa[1][bt] >> (r * 16)));
            g2 += b2f((u16)(xa[2][bt] >> (r * 16)));
            g3 += b2f((u16)(xa[3][bt] >> (r * 16)));
          } else { g0 += br[r]; g1 += br[4 + r]; g2 += br[8 + r]; g3 += br[12 + r]; }
          float cn = sigm(g1) * creg[bt][r] + sigm(g0) * tanh_f(g2);
          float h = sigm(g3) * tanh_f(cn);
          creg[bt][r] = cn;
          hp |= (u64)f2b(h) << (r * 16);
        }
        sta64((u64*)(hw + (size_t)(rg * 64 + bt * 16 + fr) * 256 + hcol), hp);
      }
    } else if (stage == 1) {           // ================= B: y = h1 @ Wih2b^T ======
      // ---- poll-on-data: h1(s) = slot s+1 (poisoned until A writes) ----
      U16B hb[4][8];
      {
        const u16* hbase = h1hist + (size_t)(s + 1) * HSTR;
        u32 pend = 0xFFFFFFFFu;
        while (true) {
#pragma unroll
          for (int bt = 0; bt < 4; ++bt) {
            const u64* hp = (const u64*)(hbase + (size_t)(rg * 64 + bt * 16 + fr) * 256 +
                                         rq * 8);
#pragma unroll
            for (int kk = 0; kk < 8; ++kk)
              if (pend & (1u << (bt * 8 + kk))) {
                hb[bt][kk].q[0] = lda64(hp + kk * 4);
                hb[bt][kk].q[1] = lda64(hp + kk * 4 + 1);
              }
          }
          bool done = true;
#pragma unroll
          for (int bt = 0; bt < 4; ++bt)
#pragma unroll
            for (int kk = 0; kk < 8; ++kk)
              if (pend & (1u << (bt * 8 + kk))) {
                if (hb[bt][kk].q[0] != SENT && hb[bt][kk].q[1] != SENT)
                  pend &= ~(1u << (bt * 8 + kk));
                else done = false;
              }
          if (__all(done)) break;
          __builtin_amdgcn_s_sleep(1);
        }
      }
      f4v acc[4][4] = {};
#pragma unroll
      for (int kk = 0; kk < 8; ++kk)
#pragma unroll
        for (int q = 0; q < 4; ++q) {
          s8v wf = *(const s8v*)&wlds[((q * 4 + w) * 16 + fr) * 256 +
                                      (((kk * 4 + rq) ^ (fr & 7)) * 8)];
#pragma unroll
          for (int bt = 0; bt < 4; ++bt)
            acc[q][bt] = __builtin_amdgcn_mfma_f32_16x16x32_bf16(wf, hb[bt][kk].v,
                                                                 acc[q][bt], 0, 0, 0);
        }
      u16* yw = ybuf + (size_t)s * YSTR;
#pragma unroll
      for (int bt = 0; bt < 4; ++bt)
#pragma unroll
        for (int q = 0; q < 4; ++q) {
          u64 yp = 0;
#pragma unroll
          for (int r = 0; r < 4; ++r) yp |= (u64)f2b(acc[q][bt][r]) << (r * 16);
          sta64((u64*)(yw + (size_t)(rg * 64 + bt * 16 + fr) * 1024 + q * 256 + hcol), yp);
        }
    } else {                           // ================= C: LSTM2 (K=256) =========
      u64 xa[4][4];
      if (s >= 80) {
        const u16* xb = Xct + ((size_t)(s - 80) * 256) * 1024;
#pragma unroll
        for (int q = 0; q < 4; ++q)
#pragma unroll
          for (int bt = 0; bt < 4; ++bt)
            xa[q][bt] = *(const u64*)(xb + (size_t)(rg * 64 + bt * 16 + fr) * 1024 +
                                      q * 256 + hcol);
      }
      // ---- poll-on-data: y(s) (poisoned) + h2(s-1) = slot s (slot 0 zeros) ----
      U16B hb[4][8];
      u64 ya[4][4];
      {
        const u16* hbase = h2hist + (size_t)s * HSTR;
        const u16* yb = ybuf + (size_t)s * YSTR;
        u32 pend = 0xFFFFFFFFu, pendY = 0xFFFFu;
        while (true) {
#pragma unroll
          for (int bt = 0; bt < 4; ++bt) {
            const u64* hp = (const u64*)(hbase + (size_t)(rg * 64 + bt * 16 + fr) * 256 +
                                         rq * 8);
#pragma unroll
            for (int kk = 0; kk < 8; ++kk)
              if (pend & (1u << (bt * 8 + kk))) {
                hb[bt][kk].q[0] = lda64(hp + kk * 4);
                hb[bt][kk].q[1] = lda64(hp + kk * 4 + 1);
              }
          }
#pragma unroll
          for (int q = 0; q < 4; ++q)
#pragma unroll
            for (int bt = 0; bt < 4; ++bt)
              if (pendY & (1u << (q * 4 + bt)))
                ya[q][bt] = lda64((const u64*)(yb + (size_t)(rg * 64 + bt * 16 + fr) * 1024 +
                                               q * 256 + hcol));
          bool done = true;
#pragma unroll
          for (int bt = 0; bt < 4; ++bt)
#pragma unroll
            for (int kk = 0; kk < 8; ++kk)
              if (pend & (1u << (bt * 8 + kk))) {
                if (hb[bt][kk].q[0] != SENT && hb[bt][kk].q[1] != SENT)
                  pend &= ~(1u << (bt * 8 + kk));
                else done = false;
              }
#pragma unroll
          for (int q = 0; q < 4; ++q)
#pragma unroll
            for (int bt = 0; bt < 4; ++bt)
              if (pendY & (1u << (q * 4 + bt))) {
                if (ya[q][bt] != SENT) pendY &= ~(1u << (q * 4 + bt));
                else done = false;
              }
          if (__all(done)) break;
          __builtin_amdgcn_s_sleep(1);
        }
      }
      f4v acc[4][4] = {};
#pragma unroll
      for (int kk = 0; kk < 8; ++kk)
#pragma unroll
        for (int q = 0; q < 4; ++q) {
          s8v wf = *(const s8v*)&wlds[((q * 4 + w) * 16 + fr) * 256 +
                                      (((kk * 4 + rq) ^ (fr & 7)) * 8)];
#pragma unroll
          for (int bt = 0; bt < 4; ++bt)
            acc[q][bt] = __builtin_amdgcn_mfma_f32_16x16x32_bf16(wf, hb[bt][kk].v,
                                                                 acc[q][bt], 0, 0, 0);
        }
      u16* hw = h2hist + (size_t)(s + 1) * HSTR;
#pragma unroll
      for (int bt = 0; bt < 4; ++bt) {
        u64 hp = 0;
#pragma unroll
        for (int r = 0; r < 4; ++r) {
          float g0 = acc[0][bt][r] + b2f((u16)(ya[0][bt] >> (r * 16)));
          float g1 = acc[1][bt][r] + b2f((u16)(ya[1][bt] >> (r * 16)));
          float g2 = acc[2][bt][r] + b2f((u16)(ya[2][bt] >> (r * 16)));
          float g3 = acc[3][bt][r] + b2f((u16)(ya[3][bt] >> (r * 16)));
          if (s >= 80) {
            g0 += b2f((u16)(xa[0][bt] >> (r * 16)));
            g1 += b2f((u16)(xa[1][bt] >> (r * 16)));
            g2 += b2f((u16)(xa[2][bt] >> (r * 16)));
            g3 += b2f((u16)(xa[3][bt] >> (r * 16)));
          } else { g0 += br[r]; g1 += br[4 + r]; g2 += br[8 + r]; g3 += br[12 + r]; }
          float cn = sigm(g1) * creg[bt][r] + sigm(g0) * tanh_f(g2);
          float h = sigm(g3) * tanh_f(cn);
          creg[bt][r] = cn;
          hp |= (u64)f2b(h) << (r * 16);
        }
        sta64((u64*)(hw + (size_t)(rg * 64 + bt * 16 + fr) * 256 + hcol), hp);
      }
    }
  }
}

// ---------------- combine per-tile LSE partials -> per-row NLL -------------------------
__global__ __launch_bounds__(256) void nll_combine(const float* __restrict__ pm,
                                                   const float* __restrict__ ps,
                                                   const float* __restrict__ tgtlog,
                                                   float* __restrict__ rowloss) {
  int row = blockIdx.x * 256 + threadIdx.x;
  if (row >= 9984) return;
  const float* pmr = pm + (size_t)row * 48;
  const float* psr = ps + (size_t)row * 48;
  float M = -1e30f;
#pragma unroll
  for (int t = 0; t < 48; ++t) M = fmaxf(M, pmr[t]);
  float S = 0.f;
#pragma unroll
  for (int t = 0; t < 48; ++t) S += psr[t] * __expf(pmr[t] - M);
  rowloss[row] = M + __logf(S) - tgtlog[row];
}

__global__ __launch_bounds__(256) void final_kernel(const float* __restrict__ rowloss,
                                                    float* __restrict__ out) {
  float s = 0.f;
  for (int n = threadIdx.x; n < 9984; n += 256) s += rowloss[n];
#pragma unroll
  for (int o = 1; o < 64; o <<= 1) s += __shfl_xor(s, o);
  __shared__ float sr[4];
  if ((threadIdx.x & 63) == 0) sr[threadIdx.x >> 6] = s;
  __syncthreads();
  if (threadIdx.x == 0) out[0] = (sr[0] + sr[1] + sr[2] + sr[3]) * (1.f / 256.f);
}

// ---------------------------------------------------------------------------------------
extern "C" void kernel_launch(void* const* d_in, const int* in_sizes, int n_in,
                              void* d_out, int out_size, void* d_ws, size_t ws_size,
                              hipStream_t stream) {
  const float* feat    = (const float*)d_in[0];
  const float* caption = (const float*)d_in[1];
  const float* coh     = (const float*)d_in[2];
  const float* W_ih1   = (const float*)d_in[3];
  const float* W_hh1   = (const float*)d_in[4];
  const float* b_ih1   = (const float*)d_in[5];
  const float* b_hh1   = (const float*)d_in[6];
  const float* W_ih2   = (const float*)d_in[7];
  const float* W_hh2   = (const float*)d_in[8];
  const float* b_ih2   = (const float*)d_in[9];
  const float* b_hh2   = (const float*)d_in[10];
  const float* W_out   = (const float*)d_in[11];
  const float* b_out   = (const float*)d_in[12];

  char* p = (char*)d_ws;
  auto take = [&](size_t bytes) { char* r = p; p += (bytes + 255) & ~(size_t)255; return r; };
  u16* X1t    = (u16*)take(80ull * 256 * 1024 * 2);    // 41.9 MB, time-major
  u16* Xct    = (u16*)take(40ull * 256 * 1024 * 2);    // 21.0 MB
  u16* h1hist = (u16*)take(120ull * HSTR * 2);         // 15.7 MB
  u16* h2hist = (u16*)take(120ull * HSTR * 2);         // 15.7 MB (slots 81.. = H2dec)
  u16* Wih1b  = (u16*)take(1024ull * 4096 * 2);
  u16* Wih2ab = (u16*)take(1024ull * 256 * 2);
  u16* Woutb  = (u16*)take((size_t)VOCP * 256 * 2);
  u16* Wpk    = (u16*)take(786432ull * 2);             // 1.5 MB packed recur weights
  float* b1sum = (float*)take(1024 * 4);
  float* b2sum = (float*)take(1024 * 4);
  float* boutp = (float*)take(VOCP * 4);
  int*   tgt   = (int*)take(9984 * 4);
  float* tgtlog = (float*)take(9984 * 4);
  float* pm    = (float*)take(9984ull * 48 * 4);
  float* ps    = (float*)take(9984ull * 48 * 4);
  float* rowloss = (float*)take(9984 * 4);
  // union region (84 MB): capT/featT (pre-recurrence) then ybuf (recurrence)
  char* uni = take(10240ull * 4096 * 2);
  u16* capT  = (u16*)uni;
  u16* featT = (u16*)uni;
  u16* ybuf  = (u16*)uni;            // 119 * YSTR * 2 = 62.4 MB

  // h slot 0 = zeros; slots 1..119 = sentinel poison (re-done every launch)
  hipMemsetAsync(h1hist, 0, HSTR * 2, stream);
  hipMemsetAsync(h1hist + HSTR, 0xFF, 119ull * HSTR * 2, stream);
  hipMemsetAsync(h2hist, 0, HSTR * 2, stream);
  hipMemsetAsync(h2hist + HSTR, 0xFF, 119ull * HSTR * 2, stream);

  bias_setup<<<dim3(24), dim3(256), 0, stream>>>(b_ih1, b_hh1, b_ih2, b_hh2, b_out,
                                                 b1sum, b2sum, boutp);
  auto pack = [&](u16* dst, int dld, int doff, const float* src, int sld, int soff,
                  int Wc, int R, int Rs) {
    int tot = Wc * R;
    pack_bf16<<<dim3((tot + 255) / 256), dim3(256), 0, stream>>>(dst, dld, doff, src, sld, soff,
                                                                 Wc, R, Rs);
  };
  pack(Wih1b, 4096, 0, W_ih1, 4096, 0, 4096, 1024, 1024);
  pack(Wih2ab, 256, 0, W_ih2, 512, 0, 256, 1024, 1024);     // W_ih2[:, :256]
  pack(Woutb, 256, 0, W_out, 256, 0, 256, VOCP, VOC);
  wpack<<<dim3(3072), dim3(256), 0, stream>>>(Wpk, W_hh1, W_ih2, W_hh2);

  argmax_kernel<<<dim3(39 * 256), dim3(256), 0, stream>>>(coh, tgt);

  // caption -> capT (time-major bf16) -> Xct (b2 folded)
  conv_tr<<<dim3(10240), dim3(256), 0, stream>>>(caption, capT, 40, 256, 0);
  gemm_bb<0><<<dim3(80, 4), dim3(256), 0, stream>>>(capT, Wih2ab, b2sum, Xct,
                                                    nullptr, nullptr, nullptr, 256, 0);
  // feat -> featT (time-major bf16, 2 chunks) -> X1t (b1 folded)
  for (int c = 0; c < 2; ++c) {
    conv_tr<<<dim3(10240), dim3(256), 0, stream>>>(feat, featT, 80, 4096, c * 40);
    gemm_bb<0><<<dim3(80, 4), dim3(256), 0, stream>>>(featT, Wih1b, b1sum, X1t,
                                                      nullptr, nullptr, nullptr, 4096,
                                                      c * 10240);
  }

  // ybuf reuses the featT region: poison AFTER the GEMMs (stream-ordered)
  hipMemsetAsync(ybuf, 0xFF, 119ull * YSTR * 2, stream);

  // whole 119-step recurrence: 48 blocks (A/B/C stages), sentinel-data pipeline
  recur_kernel<<<dim3(48), dim3(256), 0, stream>>>(X1t, Xct, b1sum, b2sum, Wpk,
                                                   h1hist, h2hist, ybuf);

  // logits GEMM (A = h2 decode slots) with fused LSE partials + target logit
  gemm_bb<2><<<dim3(78, 24), dim3(256), 0, stream>>>(h2hist + 81ull * HSTR, Woutb, boutp, pm,
                                                     ps, tgtlog, tgt, 256, 0);
  nll_combine<<<dim3(39), dim3(256), 0, stream>>>(pm, ps, tgtlog, rowloss);
  final_kernel<<<dim3(1), dim3(256), 0, stream>>>(rowloss, (float*)d_out);
}

// Round 10
// 2470.922 us; speedup vs baseline: 2.2503x; 2.2503x over previous
//
#include <hip/hip_runtime.h>

// Net_39135742001869: S2VT video-caption LSTM (enc 80 + dec 39 steps), bf16 MFMA.
// R10: R4's proven recurrence VERBATIM (1010us) + L2-pinned encoder/logits GEMMs,
// time-major conv, simple epilogues. Recurrence untouched this round.

typedef unsigned short u16;
typedef unsigned int u32;
typedef unsigned long long u64;
typedef __attribute__((ext_vector_type(8))) short s8v;   // 8 x bf16
typedef __attribute__((ext_vector_type(4))) float f4v;   // MFMA accumulator

#define VOC   6000
#define VOCP  6144
#define HSTR  65536       // 256*256 h-history slot stride (elems)

__device__ __forceinline__ u16 f2b(float f) {
  unsigned u = __float_as_uint(f);
  return (u16)((u + 0x7fffu + ((u >> 16) & 1u)) >> 16);   // RNE f32->bf16
}
__device__ __forceinline__ float b2f(u16 u) { return __uint_as_float(((unsigned)u) << 16); }
__device__ __forceinline__ float sigm(float x) { return 1.f / (1.f + __expf(-x)); }
__device__ __forceinline__ float tanh_f(float x) {
  float e = __expf(-2.f * fabsf(x));
  float t = (1.f - e) / (1.f + e);
  return x >= 0.f ? t : -t;
}

// ---------------- f32 -> bf16 row-permuted conversion: dst[tl*256+b] = src[b*T+toff+tl]
__global__ __launch_bounds__(256) void conv_tr(const float* __restrict__ src,
                                               u16* __restrict__ dst, int T, int D, int toff) {
  const int tl = blockIdx.x >> 8, b = blockIdx.x & 255;
  const float* s = src + ((size_t)b * T + toff + tl) * D;
  u16* d = dst + (size_t)blockIdx.x * D;
  for (int i = threadIdx.x * 8; i < D; i += 2048) {
    float4 a = *(const float4*)(s + i);
    float4 c = *(const float4*)(s + i + 4);
    unsigned w0 = (unsigned)f2b(a.x) | ((unsigned)f2b(a.y) << 16);
    unsigned w1 = (unsigned)f2b(a.z) | ((unsigned)f2b(a.w) << 16);
    unsigned w2 = (unsigned)f2b(c.x) | ((unsigned)f2b(c.y) << 16);
    unsigned w3 = (unsigned)f2b(c.z) | ((unsigned)f2b(c.w) << 16);
    *(int4*)(d + i) = make_int4((int)w0, (int)w1, (int)w2, (int)w3);
  }
}

// ---------------- weight pack (f32 -> bf16, strided slice + zero pad rows) -------------
__global__ void pack_bf16(u16* __restrict__ dst, int dld, int doff,
                          const float* __restrict__ src, int sld, int soff,
                          int Wc, int R, int Rsrc) {
  int i = blockIdx.x * 256 + threadIdx.x;
  if (i >= Wc * R) return;
  int r = i / Wc, c = i - r * Wc;
  float v = (r < Rsrc) ? src[(size_t)r * sld + soff + c] : 0.f;
  dst[(size_t)r * dld + doff + c] = f2b(v);
}

__global__ void bias_setup(const float* __restrict__ bi1, const float* __restrict__ bh1,
                           const float* __restrict__ bi2, const float* __restrict__ bh2,
                           const float* __restrict__ bo,
                           float* __restrict__ b1s, float* __restrict__ b2s,
                           float* __restrict__ bop) {
  int i = blockIdx.x * 256 + threadIdx.x;
  if (i < 1024) { b1s[i] = bi1[i] + bh1[i]; b2s[i] = bi2[i] + bh2[i]; }
  if (i < VOCP) bop[i] = (i < VOC) ? bo[i] : -1e30f;
}

// ---------------- targets = argmax(caption_one_hot[b, d+1, :]) -------------------------
__global__ __launch_bounds__(256) void argmax_kernel(const float* __restrict__ coh,
                                                     int* __restrict__ tgt) {
  const int d = blockIdx.x >> 8;
  const int b = blockIdx.x & 255;
  const float4* row = (const float4*)(coh + ((size_t)b * 40 + (d + 1)) * VOC);
  float best = -3.4e38f; int bi = 0;
  for (int v = threadIdx.x; v < VOC / 4; v += 256) {
    float4 x = row[v];
    float vals[4] = {x.x, x.y, x.z, x.w};
#pragma unroll
    for (int j = 0; j < 4; ++j)
      if (vals[j] > best) { best = vals[j]; bi = v * 4 + j; }
  }
#pragma unroll
  for (int o = 1; o < 64; o <<= 1) {
    float ov = __shfl_xor(best, o);
    int   oi = __shfl_xor(bi, o);
    if (ov > best || (ov == best && oi < bi)) { best = ov; bi = oi; }
  }
  __shared__ float sv[4]; __shared__ int si[4];
  if ((threadIdx.x & 63) == 0) { sv[threadIdx.x >> 6] = best; si[threadIdx.x >> 6] = bi; }
  __syncthreads();
  if (threadIdx.x == 0) {
    for (int i = 1; i < 4; ++i)
      if (sv[i] > best || (sv[i] == best && si[i] < bi)) { best = sv[i]; bi = si[i]; }
    tgt[blockIdx.x] = bi;   // [d][b]
  }
}

// ---------------- GEMM: acc = A_bf16[M][K] * Bw_bf16[N][K]^T (+bias) -------------------
// MODE 0: X-GEMM. grid.x = 320 linear; xcd = bid&7 pins n-tile = xcd&3 so each XCD's
//         2MB B-slice stays L2-resident; m-tile = (xcd>>2)*40 + bid>>3. M=10240, N=1024.
//         Epilogue: time-major bf16 row (moff + m) with ld 1024.
// MODE 2: logits. grid.x = 1872 linear; m = bid/24, n = bid%24 (24%8==0 -> each XCD
//         sees 3 fixed 128KB B-slices). Fused NLL partials + target-logit extraction.
template <int MODE>
__global__ __launch_bounds__(256) void gemm_bb(
    const u16* __restrict__ A, const u16* __restrict__ Bw,
    const float* __restrict__ bias, void* __restrict__ out0,
    float* __restrict__ ps, float* __restrict__ tgtlog, const int* __restrict__ tgt,
    int K, int moff)
{
  int mt, nt;
  if (MODE == 0) {
    const int xcd = (int)blockIdx.x & 7;
    nt = xcd & 3;
    mt = (xcd >> 2) * 40 + ((int)blockIdx.x >> 3);
  } else {
    mt = (int)blockIdx.x / 24;
    nt = (int)blockIdx.x % 24;
  }
  const int m0 = mt * 128;
  const int n0 = nt * 256;
  const int tid = threadIdx.x;
  const int lane = tid & 63;
  const int wid = tid >> 6;
  const int wm = wid >> 1, wn = wid & 1;
  const int fr = lane & 15;
  const int fk = (lane >> 4) * 8;
  const int rq = lane >> 4;

  __shared__ u16 As[128][72];
  __shared__ u16 Bs[256][72];
  f4v acc[4][8] = {};

  const int ar = tid >> 1, ac = (tid & 1) * 32;
  int4 av[4], bv[8];
  {
    const u16* ap = A + (size_t)(m0 + ar) * K + ac;
    const u16* bp = Bw + (size_t)(n0 + tid) * K;
#pragma unroll
    for (int v = 0; v < 4; ++v) av[v] = *(const int4*)(ap + v * 8);
#pragma unroll
    for (int v = 0; v < 8; ++v) bv[v] = *(const int4*)(bp + v * 8);
  }
#pragma unroll 1
  for (int k0 = 0; k0 < K; k0 += 64) {
    __syncthreads();
#pragma unroll
    for (int v = 0; v < 4; ++v) *(int4*)&As[ar][ac + v * 8] = av[v];
#pragma unroll
    for (int v = 0; v < 8; ++v) *(int4*)&Bs[tid][v * 8] = bv[v];
    __syncthreads();
    if (k0 + 64 < K) {
      const u16* ap = A + (size_t)(m0 + ar) * K + k0 + 64 + ac;
      const u16* bp = Bw + (size_t)(n0 + tid) * K + k0 + 64;
#pragma unroll
      for (int v = 0; v < 4; ++v) av[v] = *(const int4*)(ap + v * 8);
#pragma unroll
      for (int v = 0; v < 8; ++v) bv[v] = *(const int4*)(bp + v * 8);
    }
#pragma unroll
    for (int ks = 0; ks < 2; ++ks) {
      const int kb = ks * 32 + fk;
      s8v a[4], b[8];
#pragma unroll
      for (int i = 0; i < 4; ++i) a[i] = *(const s8v*)&As[wm * 64 + i * 16 + fr][kb];
#pragma unroll
      for (int j = 0; j < 8; ++j) b[j] = *(const s8v*)&Bs[wn * 128 + j * 16 + fr][kb];
#pragma unroll
      for (int i = 0; i < 4; ++i)
#pragma unroll
        for (int j = 0; j < 8; ++j)
          acc[i][j] = __builtin_amdgcn_mfma_f32_16x16x32_bf16(a[i], b[j], acc[i][j], 0, 0, 0);
    }
  }

  float bz[8];
#pragma unroll
  for (int j = 0; j < 8; ++j) bz[j] = bias[n0 + wn * 128 + j * 16 + fr];

  if (MODE == 2) {
    const int tile = nt * 2 + wn;
    float* pm = (float*)out0;
#pragma unroll
    for (int i = 0; i < 4; ++i) {
#pragma unroll
      for (int r = 0; r < 4; ++r) {
        const int row = m0 + wm * 64 + i * 16 + rq * 4 + r;
        const int tg = tgt[row];
        float vj[8]; float m = -1e30f;
#pragma unroll
        for (int j = 0; j < 8; ++j) {
          const int n = n0 + wn * 128 + j * 16 + fr;
          float v = acc[i][j][r] + bz[j];
          vj[j] = v;
          m = fmaxf(m, v);
          if (n == tg) tgtlog[row] = v;
        }
#pragma unroll
        for (int o = 1; o < 16; o <<= 1) m = fmaxf(m, __shfl_xor(m, o));
        float s = 0.f;
#pragma unroll
        for (int j = 0; j < 8; ++j) s += __expf(vj[j] - m);
#pragma unroll
        for (int o = 1; o < 16; o <<= 1) s += __shfl_xor(s, o);
        if (fr == 0) { pm[(size_t)row * 48 + tile] = m; ps[(size_t)row * 48 + tile] = s; }
      }
    }
  } else {
    u16* X = (u16*)out0;
#pragma unroll
    for (int i = 0; i < 4; ++i)
#pragma unroll
      for (int r = 0; r < 4; ++r) {
        const int row = moff + m0 + wm * 64 + i * 16 + rq * 4 + r;
        u16* crow = X + (size_t)row * 1024;
#pragma unroll
        for (int j = 0; j < 8; ++j)
          crow[n0 + wn * 128 + j * 16 + fr] = f2b(acc[i][j][r] + bz[j]);
      }
  }
}

// ---------------- R4 recurrence, VERBATIM (measured 1010 us) ---------------------------
// 128 blocks x 128 threads. Blocks 0..63: phase1 (LSTM1), 64..127: phase2 (LSTM2).
// Block (bm 0..3, bh 0..15) owns batch quarter bm (64 rows) x h-cols [bh*16, bh*16+16).
// History buffers h1hist/h2hist[120][256][256] bf16; slot s+1 = h(s); slot 0 = zeros.
// Producer: sc1-store h slice -> drain vmcnt -> relaxed flag store f[bm*16+bh] = s+1.
// Consumer: poll one 64B flag line (16 lanes, read-only; no RMW serialization).
__global__ __launch_bounds__(128, 1) void recur_kernel(
    const u16* __restrict__ X1t,      // [80][256][1024] bf16, bias folded
    const u16* __restrict__ Xct,      // [40][256][1024] bf16, bias folded
    const float* __restrict__ b1sum, const float* __restrict__ b2sum,
    const u16* __restrict__ Whh1,     // [1024][256] bf16
    const u16* __restrict__ Wcat2,    // [1024][512] bf16 = [W_ih2[:,256:] | W_hh2]
    u16* __restrict__ h1hist,         // [120][256][256] bf16
    u16* __restrict__ h2hist,         // [120][256][256] bf16 (slots 81.. = H2dec)
    u32* __restrict__ f1, u32* __restrict__ f2)
{
  __shared__ u16 wlds[64 * 512];      // weight slice, rotation-swizzled
  const int tid = threadIdx.x;
  const int lane = tid & 63;
  const int w = tid >> 6;             // wave 0..1
  const int fr = lane & 15;
  const int fk8 = lane >> 4;          // k-quarter 0..3
  const int fk = fk8 * 8;
  const int rq = lane >> 4;
  const bool p2 = blockIdx.x >= 64;
  const int bb = p2 ? (int)blockIdx.x - 64 : (int)blockIdx.x;
  const int bm = bb >> 4;             // batch quarter
  const int bh = bb & 15;             // h-dim 16-col tile
  const int hd = bh * 16 + fr;
  const int LD = p2 ? 512 : 256;
  const int C8m = (p2 ? 64 : 32) - 1; // 16B-granule index mask per row
  const int KK = p2 ? 16 : 8;

  // one-time: weight slice -> LDS, rotation swizzle pg = (c8 + 4*row) & C8m
  {
    const u16* Wsrc = p2 ? Wcat2 : Whh1;
    const int C8 = C8m + 1;
    for (int idx = tid; idx < 64 * C8; idx += 128) {
      int l = idx / C8, c8 = idx - l * C8;
      int gr = (l >> 4) * 256 + bh * 16 + (l & 15);
      int4 v = *(const int4*)(Wsrc + (size_t)gr * LD + c8 * 8);
      *(int4*)&wlds[l * LD + (((c8 + 4 * l) & C8m) * 8)] = v;
    }
  }
  float br4[4];
  {
    const float* bsrc = p2 ? b2sum : b1sum;
#pragma unroll
    for (int q = 0; q < 4; ++q) br4[q] = bsrc[q * 256 + hd];
  }
  __syncthreads();

  float creg[2][4] = {};
  u32* myflag = (p2 ? f2 : f1) + bm * 16 + bh;

#pragma unroll 1
  for (int s = 0; s < 119; ++s) {
    // ---- gate addend (X or bias) issued BEFORE the poll so it overlaps the wait ----
    const u16* Xb = nullptr;
    if (!p2 && s < 80)  Xb = X1t + (size_t)s * 262144;
    if (p2  && s >= 80) Xb = Xct + (size_t)(s - 80) * 262144;
    float ga[2][4][4];
    if (Xb) {
#pragma unroll
      for (int i = 0; i < 2; ++i)
#pragma unroll
        for (int r = 0; r < 4; ++r) {
          const int bat = bm * 64 + w * 32 + i * 16 + rq * 4 + r;
          const u16* xp = Xb + (size_t)bat * 1024;
#pragma unroll
          for (int q = 0; q < 4; ++q) ga[i][r][q] = b2f(xp[q * 256 + hd]);
        }
    } else {
#pragma unroll
      for (int i = 0; i < 2; ++i)
#pragma unroll
        for (int r = 0; r < 4; ++r)
#pragma unroll
          for (int q = 0; q < 4; ++q) ga[i][r][q] = br4[q];
    }
    // ---- watermark wait (lanes 0..15 f1, 16..31 f2 if p2; read-only) ----
    if (p2 || s > 0) {
      const u32 tA = p2 ? (u32)(s + 1) : (u32)s;
      const u32 tB = (u32)s;
      while (true) {
        bool ok = true;
        if (lane < 16)
          ok = __hip_atomic_load(&f1[bm * 16 + lane], __ATOMIC_RELAXED,
                                 __HIP_MEMORY_SCOPE_AGENT) >= tA;
        else if (p2 && lane < 32)
          ok = __hip_atomic_load(&f2[bm * 16 + (lane - 16)], __ATOMIC_RELAXED,
                                 __HIP_MEMORY_SCOPE_AGENT) >= tB;
        if (__all(ok)) break;
        __builtin_amdgcn_s_sleep(1);
      }
    }
    // ---- A fragments from history (sc1 loads bypass stale per-XCD L2) ----
    const u16* h1base = h1hist + (size_t)(p2 ? s + 1 : s) * HSTR;
    const u16* h2base = h2hist + (size_t)s * HSTR;
    s8v a[2][16];
#pragma unroll
    for (int i = 0; i < 2; ++i) {
      const int row = bm * 64 + w * 32 + i * 16 + fr;
#pragma unroll
      for (int kk = 0; kk < 16; ++kk) {
        if (kk < KK) {
          const u16* src = (kk < 8) ? (h1base + (size_t)row * 256 + kk * 32 + fk)
                                    : (h2base + (size_t)row * 256 + (kk - 8) * 32 + fk);
          union { u64 q[2]; s8v v; } u;
          u.q[0] = __hip_atomic_load((const u64*)src,     __ATOMIC_RELAXED,
                                     __HIP_MEMORY_SCOPE_AGENT);
          u.q[1] = __hip_atomic_load((const u64*)src + 1, __ATOMIC_RELAXED,
                                     __HIP_MEMORY_SCOPE_AGENT);
          a[i][kk] = u.v;
        }
      }
    }
    // ---- MFMAs (B from LDS, rotation swizzle) ----
    f4v acc[2][4] = {};
#pragma unroll
    for (int kk = 0; kk < 16; ++kk) {
      if (kk < KK) {
#pragma unroll
        for (int q = 0; q < 4; ++q) {
          const int l = q * 16 + fr;
          s8v b = *(const s8v*)&wlds[l * LD + (((kk * 4 + fk8 + 4 * l) & C8m) * 8)];
#pragma unroll
          for (int i = 0; i < 2; ++i)
            acc[i][q] = __builtin_amdgcn_mfma_f32_16x16x32_bf16(a[i][kk], b, acc[i][q], 0, 0, 0);
        }
      }
    }
    // ---- cell update + h store (paired bf16 -> one u32 sc1 store per even lane) ----
    u16* hwbase = (p2 ? h2hist : h1hist) + (size_t)(s + 1) * HSTR;
#pragma unroll
    for (int i = 0; i < 2; ++i) {
#pragma unroll
      for (int r = 0; r < 4; ++r) {
        const int bat = bm * 64 + w * 32 + i * 16 + rq * 4 + r;
        float g0 = acc[i][0][r] + ga[i][r][0], g1 = acc[i][1][r] + ga[i][r][1];
        float g2 = acc[i][2][r] + ga[i][r][2], g3 = acc[i][3][r] + ga[i][r][3];
        float cn = sigm(g1) * creg[i][r] + sigm(g0) * tanh_f(g2);
        float h = sigm(g3) * tanh_f(cn);
        creg[i][r] = cn;
        unsigned hb = f2b(h);
        unsigned ob = (unsigned)__shfl_xor((int)hb, 1);
        if ((fr & 1) == 0)
          __hip_atomic_store((u32*)(hwbase + (size_t)bat * 256 + hd), hb | (ob << 16),
                             __ATOMIC_RELAXED, __HIP_MEMORY_SCOPE_AGENT);
      }
    }
    // ---- publish watermark: drain stores, block-sync, single-writer flag ----
    asm volatile("s_waitcnt vmcnt(0)" ::: "memory");
    __syncthreads();
    if (tid == 0)
      __hip_atomic_store(myflag, (u32)(s + 1), __ATOMIC_RELAXED, __HIP_MEMORY_SCOPE_AGENT);
  }
}

// ---------------- combine per-tile LSE partials -> per-row NLL -------------------------
__global__ __launch_bounds__(256) void nll_combine(const float* __restrict__ pm,
                                                   const float* __restrict__ ps,
                                                   const float* __restrict__ tgtlog,
                                                   float* __restrict__ rowloss) {
  int row = blockIdx.x * 256 + threadIdx.x;
  if (row >= 9984) return;
  const float* pmr = pm + (size_t)row * 48;
  const float* psr = ps + (size_t)row * 48;
  float M = -1e30f;
#pragma unroll
  for (int t = 0; t < 48; ++t) M = fmaxf(M, pmr[t]);
  float S = 0.f;
#pragma unroll
  for (int t = 0; t < 48; ++t) S += psr[t] * __expf(pmr[t] - M);
  rowloss[row] = M + __logf(S) - tgtlog[row];
}

__global__ __launch_bounds__(256) void final_kernel(const float* __restrict__ rowloss,
                                                    float* __restrict__ out) {
  float s = 0.f;
  for (int n = threadIdx.x; n < 9984; n += 256) s += rowloss[n];
#pragma unroll
  for (int o = 1; o < 64; o <<= 1) s += __shfl_xor(s, o);
  __shared__ float sr[4];
  if ((threadIdx.x & 63) == 0) sr[threadIdx.x >> 6] = s;
  __syncthreads();
  if (threadIdx.x == 0) out[0] = (sr[0] + sr[1] + sr[2] + sr[3]) * (1.f / 256.f);
}

// ---------------------------------------------------------------------------------------
extern "C" void kernel_launch(void* const* d_in, const int* in_sizes, int n_in,
                              void* d_out, int out_size, void* d_ws, size_t ws_size,
                              hipStream_t stream) {
  const float* feat    = (const float*)d_in[0];
  const float* caption = (const float*)d_in[1];
  const float* coh     = (const float*)d_in[2];
  const float* W_ih1   = (const float*)d_in[3];
  const float* W_hh1   = (const float*)d_in[4];
  const float* b_ih1   = (const float*)d_in[5];
  const float* b_hh1   = (const float*)d_in[6];
  const float* W_ih2   = (const float*)d_in[7];
  const float* W_hh2   = (const float*)d_in[8];
  const float* b_ih2   = (const float*)d_in[9];
  const float* b_hh2   = (const float*)d_in[10];
  const float* W_out   = (const float*)d_in[11];
  const float* b_out   = (const float*)d_in[12];

  char* p = (char*)d_ws;
  auto take = [&](size_t bytes) { char* r = p; p += (bytes + 255) & ~(size_t)255; return r; };
  u16* X1t    = (u16*)take(80ull * 256 * 1024 * 2);    // 41.9 MB, time-major
  u16* Xct    = (u16*)take(40ull * 256 * 1024 * 2);    // 21.0 MB
  u16* h1hist = (u16*)take(120ull * HSTR * 2);         // 15.7 MB
  u16* h2hist = (u16*)take(120ull * HSTR * 2);         // 15.7 MB (slots 81.. = H2dec)
  u16* Wih1b  = (u16*)take(1024ull * 4096 * 2);        // 8 MB
  u16* Whh1b  = (u16*)take(1024ull * 256 * 2);
  u16* Wih2ab = (u16*)take(1024ull * 256 * 2);
  u16* Wcat2b = (u16*)take(1024ull * 512 * 2);
  u16* Woutb  = (u16*)take((size_t)VOCP * 256 * 2);
  float* b1sum = (float*)take(1024 * 4);
  float* b2sum = (float*)take(1024 * 4);
  float* boutp = (float*)take(VOCP * 4);
  int*   tgt   = (int*)take(9984 * 4);
  float* tgtlog = (float*)take(9984 * 4);
  float* pm    = (float*)take(9984ull * 48 * 4);
  float* ps    = (float*)take(9984ull * 48 * 4);
  float* rowloss = (float*)take(9984 * 4);
  u32* f1      = (u32*)take(256);                      // 64 flags (f2 contiguous)
  u32* f2      = (u32*)take(256);
  // union region (84 MB): capT / featT chunk — only used before the recurrence
  char* uni = take(10240ull * 4096 * 2);
  u16* capT  = (u16*)uni;            // 10240 x 256
  u16* featT = (u16*)uni;            // 10240 x 4096 per chunk

  // zero h slot 0 (both histories) and the watermark flags (f1,f2 contiguous)
  hipMemsetAsync(h1hist, 0, HSTR * 2, stream);
  hipMemsetAsync(h2hist, 0, HSTR * 2, stream);
  hipMemsetAsync(f1, 0, 512, stream);

  bias_setup<<<dim3(24), dim3(256), 0, stream>>>(b_ih1, b_hh1, b_ih2, b_hh2, b_out,
                                                 b1sum, b2sum, boutp);
  auto pack = [&](u16* dst, int dld, int doff, const float* src, int sld, int soff,
                  int Wc, int R, int Rs) {
    int tot = Wc * R;
    pack_bf16<<<dim3((tot + 255) / 256), dim3(256), 0, stream>>>(dst, dld, doff, src, sld, soff,
                                                                 Wc, R, Rs);
  };
  pack(Wih1b, 4096, 0, W_ih1, 4096, 0, 4096, 1024, 1024);
  pack(Whh1b, 256, 0, W_hh1, 256, 0, 256, 1024, 1024);
  pack(Wih2ab, 256, 0, W_ih2, 512, 0, 256, 1024, 1024);     // W_ih2[:, :256]
  pack(Wcat2b, 512, 0, W_ih2, 512, 256, 256, 1024, 1024);   // W_ih2[:, 256:]
  pack(Wcat2b, 512, 256, W_hh2, 256, 0, 256, 1024, 1024);   // W_hh2
  pack(Woutb, 256, 0, W_out, 256, 0, 256, VOCP, VOC);       // zero-padded rows

  argmax_kernel<<<dim3(39 * 256), dim3(256), 0, stream>>>(coh, tgt);

  // caption -> capT (time-major bf16) -> Xct = capT @ Wih2a^T + b2sum
  conv_tr<<<dim3(10240), dim3(256), 0, stream>>>(caption, capT, 40, 256, 0);
  gemm_bb<0><<<dim3(320), dim3(256), 0, stream>>>(capT, Wih2ab, b2sum, Xct,
                                                  nullptr, nullptr, nullptr, 256, 0);

  // feat -> featT (time-major bf16, 2 chunks) -> X1t = featT @ Wih1^T + b1sum
  for (int c = 0; c < 2; ++c) {
    conv_tr<<<dim3(10240), dim3(256), 0, stream>>>(feat, featT, 80, 4096, c * 40);
    gemm_bb<0><<<dim3(320), dim3(256), 0, stream>>>(featT, Wih1b, b1sum, X1t,
                                                    nullptr, nullptr, nullptr, 4096,
                                                    c * 10240);
  }

  // whole 119-step double-LSTM recurrence (R4 kernel, verbatim)
  recur_kernel<<<dim3(128), dim3(128), 0, stream>>>(X1t, Xct, b1sum, b2sum,
                                                    Whh1b, Wcat2b, h1hist, h2hist, f1, f2);

  // logits GEMM (A = h2 decode slots) with fused LSE partials + target logit
  gemm_bb<2><<<dim3(1872), dim3(256), 0, stream>>>(h2hist + 81ull * HSTR, Woutb, boutp, pm,
                                                   ps, tgtlog, tgt, 256, 0);
  nll_combine<<<dim3(39), dim3(256), 0, stream>>>(pm, ps, tgtlog, rowloss);
  final_kernel<<<dim3(1), dim3(256), 0, stream>>>(rowloss, (float*)d_out);
}